// Round 12
// baseline (1365.760 us; speedup 1.0000x reference)
//
#include <hip/hip_runtime.h>
#include <hip/hip_bf16.h>

// LSTMReg on MI355X — round 12: r11 (in-register gates, zbuf deleted) +
// LAYER-STAGGERED PHASES. r11 regressed because both waves on a SIMD ran
// the same phase in lockstep -> MFMA pipe idled during every gate tail
// (~2900 cyc/iter). Now waves 0-3 (L0) and 4-7 (L1) are half an iteration
// out of phase: PhaseA = L0 MFMA(t) || L1 gates(t-2); PhaseB = L0 gates(t)
// || L1 MFMA(t-1). MFMA and VALU co-schedule fully across waves on a SIMD,
// so each phase ~ max(622 MFMA, ~400 gates) cyc. z stays in registers
// across one barrier; h0/h1 double-buffered in LDS (~8 KB total).
// Per-value arithmetic order identical to r11 -> absmax 2.4e-7.

typedef short bf16x8 __attribute__((ext_vector_type(8)));
typedef short bf16x4 __attribute__((ext_vector_type(4)));
typedef float f32x4  __attribute__((ext_vector_type(4)));

#define MFMA16(A, B, C) __builtin_amdgcn_mfma_f32_16x16x32_bf16(A, B, C, 0, 0, 0)

constexpr int T_LEN = 1024;
constexpr int H     = 64;
constexpr int NCH   = 8;     // chains per block
constexpr int NTHR  = 512;   // 8 waves: wv 0-3 layer0, wv 4-7 layer1
constexpr int NBLK  = 64;    // 512 chains / 8

// x fragment buffer: [blk][t][kt(2)][lane(64)][8 shorts]  (same as r9-r11)
constexpr int    XT_SHORTS   = 2 * 64 * 8;                 // 1024 shorts per t
constexpr size_t XBLK_SHORTS = (size_t)T_LEN * XT_SHORTS;  // 2 MiB per block

__device__ __forceinline__ short f2bf(float f) {
  unsigned u = __builtin_bit_cast(unsigned, f);
  unsigned r = (u + 0x7fffu + ((u >> 16) & 1u)) >> 16;  // RNE
  return (short)r;
}
__device__ __forceinline__ float bf2f(short s) {
  unsigned u = ((unsigned)(unsigned short)s) << 16;
  return __builtin_bit_cast(float, u);
}
__device__ __forceinline__ float sigm_f(float x) {
  return __builtin_amdgcn_rcpf(1.0f + __expf(-x));
}
__device__ __forceinline__ float tanh_f(float x) {
  return 1.0f - 2.0f * __builtin_amdgcn_rcpf(1.0f + __expf(2.0f * x));
}
// neighbor-parity value: quad_perm [1,0,3,2] = xor lane bit0 (VALU pipe)
__device__ __forceinline__ float dpp_xor1(float v) {
  int o = __builtin_amdgcn_mov_dpp(__builtin_bit_cast(int, v), 0xB1, 0xF, 0xF, true);
  return __builtin_bit_cast(float, o);
}

// ---- pre-pass: pack x into B-fragment packets, col parity = hi/lo part ----
__global__ __launch_bounds__(256, 4) void xconv(const float* __restrict__ x,
                                                short* __restrict__ xf) {
  const int gid = blockIdx.x * 256 + threadIdx.x;
  const int l   = gid & 63;
  const int t   = (gid >> 6) & (T_LEN - 1);
  const int blk = gid >> 16;
  const int part = l & 1, ch = (l >> 1) & 7, f0 = (l >> 4) * 8;
  const float* src = x + ((size_t)(blk * NCH + ch) * T_LEN + t) * H + f0;
  float4 v0 = *reinterpret_cast<const float4*>(src);
  float4 v1 = *reinterpret_cast<const float4*>(src + 4);
  float4 v2 = *reinterpret_cast<const float4*>(src + 32);
  float4 v3 = *reinterpret_cast<const float4*>(src + 36);
  float a[8]  = {v0.x, v0.y, v0.z, v0.w, v1.x, v1.y, v1.z, v1.w};
  float c8[8] = {v2.x, v2.y, v2.z, v2.w, v3.x, v3.y, v3.z, v3.w};
  bf16x8 p0, p1;
#pragma unroll
  for (int e = 0; e < 8; ++e) {
    short h0 = f2bf(a[e]);
    short h1 = f2bf(c8[e]);
    if (part == 0) { p0[e] = h0; p1[e] = h1; }
    else { p0[e] = f2bf(a[e] - bf2f(h0)); p1[e] = f2bf(c8[e] - bf2f(h1)); }
  }
  short* dst = xf + (size_t)blk * XBLK_SHORTS + (size_t)t * XT_SHORTS + l * 8;
  *reinterpret_cast<bf16x8*>(dst)       = p0;  // kt0 (feats 0-31)
  *reinterpret_cast<bf16x8*>(dst + 512) = p1;  // kt1 (feats 32-63)
}

__global__ __launch_bounds__(NTHR, 2) void lstm_fused(
    const short* __restrict__ xf,
    const float* __restrict__ w_ih0, const float* __restrict__ w_hh0,
    const float* __restrict__ b_ih0, const float* __restrict__ b_hh0,
    const float* __restrict__ w_ih1, const float* __restrict__ w_hh1,
    const float* __restrict__ b_ih1, const float* __restrict__ b_hh1,
    const float* __restrict__ fc_w, const float* __restrict__ fc_b,
    float* __restrict__ out) {
  const int tid = threadIdx.x;
  const int wv  = tid >> 6;
  const int L   = wv >> 2;   // 0: layer0 waves (wv 0-3), 1: layer1 (wv 4-7)
  const int w   = wv & 3;    // wave's feat block: gate g rows 64g+16w..+16
  const int l   = tid & 63;
  const int col = l & 15;    // MFMA column = 2*chain + parity
  const int lq  = l >> 4;
  const int p   = l & 1;     // parity: 0 = hi, 1 = lo
  const int blk = blockIdx.x;

  // h buffers, fragment-linear + XOR swizzle (verified r9-r11)
  __shared__ __align__(16) short hb[2][2][2][520];  // [layer][buf][half][520]
  __shared__ float fcw_s[H];
  __shared__ float hfin[NCH][H];

  for (int i = tid; i < 2 * 2 * 2 * 520; i += NTHR) ((short*)hb)[i] = 0;
  if (tid < H) fcw_s[tid] = fc_w[tid];

  // ---- weights: gate g tile = rows 64g + 16w + col; k0 = 32kt + 8lq ----
  const float* wih = L ? w_ih1 : w_ih0;
  const float* whh = L ? w_hh1 : w_hh0;
  const float* bih = L ? b_ih1 : b_ih0;
  const float* bhh = L ? b_hh1 : b_hh0;
  bf16x8 whi[4][4], wlo[4][4];  // [gate][kt] = 128 VGPR
  f32x4  biasf[4];
#pragma unroll
  for (int g = 0; g < 4; ++g) {
#pragma unroll
    for (int kt = 0; kt < 4; ++kt) {
      const int row = 64 * g + 16 * w + col;
      const int k0  = 32 * kt + 8 * lq;
      const float* src = (k0 < 64) ? &wih[row * 64 + k0] : &whh[row * 64 + (k0 - 64)];
      float4 v0 = *reinterpret_cast<const float4*>(src);
      float4 v1 = *reinterpret_cast<const float4*>(src + 4);
      float vv[8] = {v0.x, v0.y, v0.z, v0.w, v1.x, v1.y, v1.z, v1.w};
      bf16x8 hi8, lo8;
#pragma unroll
      for (int e = 0; e < 8; ++e) {
        short hh = f2bf(vv[e]);
        hi8[e] = hh;
        lo8[e] = f2bf(vv[e] - bf2f(hh));
      }
      whi[g][kt] = hi8;
      wlo[g][kt] = lo8;
    }
#pragma unroll
    for (int r = 0; r < 4; ++r) {
      int row = 64 * g + 16 * w + 4 * lq + r;
      biasf[g][r] = bih[row] + bhh[row];
    }
  }

  __syncthreads();  // hb zeros visible

  // reader LDS offset (shorts): swizzled slot * 8 (verified r9)
  const int rdoff = ((l & 48) | ((l & 15) ^ ((l >> 4) << 1))) * 8;
  // writer: this lane produces h[feat0..feat0+3] for chain col>>1, part p
  const int feat0 = 16 * w + 4 * lq;
  const int q0    = (feat0 >> 3) & 3;
  const int woff  = (feat0 >> 5) * 520 + ((q0 << 4) | (col ^ (q0 << 1))) * 8 + (feat0 & 7);

  // x prefetch (L0 waves)
  const short* xfl = xf + (size_t)blk * XBLK_SHORTS + l * 8;
  bf16x8 xb0, xb1, xbn0, xbn1;
  if (L == 0) {
    xb0 = *reinterpret_cast<const bf16x8*>(xfl);
    xb1 = *reinterpret_cast<const bf16x8*>(xfl + 512);
  }

  f32x4 cst = {0.f, 0.f, 0.f, 0.f};
  f32x4 a0, a1, a2, a3;  // z accumulators; live across one barrier
  const f32x4 zf4 = {0.f, 0.f, 0.f, 0.f};

  // 8 MFMAs per k-tile (4 gates x hi/lo); per-acc order == r9-r11.
#define KT8(kt, B_)                                                   \
  a0 = MFMA16(whi[0][kt], B_, a0); a1 = MFMA16(whi[1][kt], B_, a1);   \
  a2 = MFMA16(whi[2][kt], B_, a2); a3 = MFMA16(whi[3][kt], B_, a3);   \
  a0 = MFMA16(wlo[0][kt], B_, a0); a1 = MFMA16(wlo[1][kt], B_, a1);   \
  a2 = MFMA16(wlo[2][kt], B_, a2); a3 = MFMA16(wlo[3][kt], B_, a3);

  // gates on (a0..a3) -> hv; parity-pair DPP sum + bias, torch order i,f,g,o
#define GATES(hv_)                                                    \
  {                                                                   \
    _Pragma("unroll")                                                 \
    for (int r = 0; r < 4; ++r) {                                     \
      float z0 = (a0[r] + dpp_xor1(a0[r])) + biasf[0][r];             \
      float z1 = (a1[r] + dpp_xor1(a1[r])) + biasf[1][r];             \
      float z2 = (a2[r] + dpp_xor1(a2[r])) + biasf[2][r];             \
      float z3 = (a3[r] + dpp_xor1(a3[r])) + biasf[3][r];             \
      float ig = sigm_f(z0), fg = sigm_f(z1);                         \
      float gg = tanh_f(z2), og = sigm_f(z3);                         \
      cst[r] = fg * cst[r] + ig * gg;                                 \
      hv_[r] = og * tanh_f(cst[r]);                                   \
    }                                                                 \
  }

#define HSTORE(dst_base, hv_)                                         \
  {                                                                   \
    bf16x4 o4;                                                        \
    _Pragma("unroll")                                                 \
    for (int r = 0; r < 4; ++r) {                                     \
      short hi = f2bf(hv_[r]);                                        \
      o4[r] = p ? f2bf(hv_[r] - bf2f(hi)) : hi;                       \
    }                                                                 \
    *reinterpret_cast<bf16x4*>((dst_base) + woff) = o4;               \
  }

  for (int t = 0; t <= T_LEN + 1; ++t) {
    // ================= Phase A: L0 MFMA(t) || L1 gates(t-2) =================
    if (L == 0) {
      if (t + 1 < T_LEN) {  // issue x[t+1] loads early
        const short* px = xfl + (size_t)(t + 1) * XT_SHORTS;
        xbn0 = *reinterpret_cast<const bf16x8*>(px);
        xbn1 = *reinterpret_cast<const bf16x8*>(px + 512);
      }
      if (t < T_LEN) {
        const short* h0c = &hb[0][(t + 1) & 1][0][0];  // h0[t-1]
        bf16x8 B2 = *reinterpret_cast<const bf16x8*>(h0c + rdoff);
        bf16x8 B3 = *reinterpret_cast<const bf16x8*>(h0c + 520 + rdoff);
        a0 = zf4; a1 = zf4; a2 = zf4; a3 = zf4;
        KT8(0, xb0) KT8(1, xb1) KT8(2, B2) KT8(3, B3)
      }
    } else {
      if (t >= 2) {  // gates for step t-2 (z in regs from prev Phase B)
        f32x4 hv;
        GATES(hv)
        if (t == T_LEN + 1) {
          if (p == 0) *reinterpret_cast<f32x4*>(&hfin[col >> 1][feat0]) = hv;
        } else {
          HSTORE(&hb[1][t & 1][0][0], hv)  // h1[t-2] -> buf (t-2)&1 == t&1
        }
      }
    }

    __syncthreads();

    // ================= Phase B: L0 gates(t) || L1 MFMA(t-1) =================
    if (L == 0) {
      if (t < T_LEN) {
        f32x4 hv;
        GATES(hv)
        HSTORE(&hb[0][t & 1][0][0], hv)  // h0[t]
      }
    } else {
      if (t >= 1 && t <= T_LEN) {
        const short* h0c = &hb[0][(t + 1) & 1][0][0];  // h0[t-1]
        const short* h1c = &hb[1][t & 1][0][0];        // h1[t-2]
        bf16x8 B0 = *reinterpret_cast<const bf16x8*>(h0c + rdoff);
        bf16x8 B1 = *reinterpret_cast<const bf16x8*>(h0c + 520 + rdoff);
        bf16x8 B2 = *reinterpret_cast<const bf16x8*>(h1c + rdoff);
        bf16x8 B3 = *reinterpret_cast<const bf16x8*>(h1c + 520 + rdoff);
        a0 = zf4; a1 = zf4; a2 = zf4; a3 = zf4;
        KT8(0, B0) KT8(1, B1) KT8(2, B2) KT8(3, B3)
      }
    }

    __syncthreads();
    if (L == 0) { xb0 = xbn0; xb1 = xbn1; }
  }
#undef KT8
#undef GATES
#undef HSTORE

  // ---- FC epilogue ----
  if (tid < NCH) {
    float acc = fc_b[0];
#pragma unroll
    for (int h = 0; h < H; ++h) acc += fcw_s[h] * hfin[tid][h];
    out[blk * NCH + tid] = acc;
  }
}

extern "C" void kernel_launch(void* const* d_in, const int* in_sizes, int n_in,
                              void* d_out, int out_size, void* d_ws, size_t ws_size,
                              hipStream_t stream) {
  const float* x     = (const float*)d_in[0];
  const float* w_ih0 = (const float*)d_in[1];
  const float* w_hh0 = (const float*)d_in[2];
  const float* b_ih0 = (const float*)d_in[3];
  const float* b_hh0 = (const float*)d_in[4];
  const float* w_ih1 = (const float*)d_in[5];
  const float* w_hh1 = (const float*)d_in[6];
  const float* b_ih1 = (const float*)d_in[7];
  const float* b_hh1 = (const float*)d_in[8];
  const float* fc_w  = (const float*)d_in[9];
  const float* fc_b  = (const float*)d_in[10];
  float* out = (float*)d_out;

  short* xfrag = (short*)d_ws;  // 128 MiB exactly

  xconv<<<dim3(16384), dim3(256), 0, stream>>>(x, xfrag);
  lstm_fused<<<dim3(NBLK), dim3(NTHR), 0, stream>>>(
      xfrag, w_ih0, w_hh0, b_ih0, b_hh0, w_ih1, w_hh1, b_ih1, b_hh1,
      fc_w, fc_b, out);
}

// Round 13
// 1094.172 us; speedup vs baseline: 1.2482x; 1.2482x over previous
//
#include <hip/hip_runtime.h>
#include <hip/hip_bf16.h>

// LSTMReg on MI355X — round 13: r10 champion + DPP parity-presum of z.
// r10 audit: three pipes each ~50% (MFMA 1242 cyc/SIMD-iter, VALU ~1150,
// LDS ~1300 cyc/CU-iter) serialized in two phases; biggest removable cost is
// the z LDS round-trip (32 b128 writes + 128 scalar gate reads). MFMA waves
// now DPP-sum the (even,odd)-column z partials in-register and only even
// lanes write -> zp halves, gate threads read 4 scalars (stride-1, conflict-
// free) instead of 8. Order (ze+zo)+bias preserved -> bit-exact vs r10.

typedef short bf16x8 __attribute__((ext_vector_type(8)));
typedef float f32x4  __attribute__((ext_vector_type(4)));

#define MFMA16(A, B, C) __builtin_amdgcn_mfma_f32_16x16x32_bf16(A, B, C, 0, 0, 0)

constexpr int T_LEN = 1024;
constexpr int H     = 64;
constexpr int NCH   = 8;     // chains per block
constexpr int NTHR  = 1024;  // 16 waves
constexpr int NBLK  = 64;    // 512 chains / 8

// x fragment buffer: [blk][t][kt(2)][lane(64)][8 shorts]
constexpr int    XT_SHORTS   = 2 * 64 * 8;                 // 1024 shorts per t
constexpr size_t XBLK_SHORTS = (size_t)T_LEN * XT_SHORTS;  // 2 MiB per block

__device__ __forceinline__ short f2bf(float f) {
  unsigned u = __builtin_bit_cast(unsigned, f);
  unsigned r = (u + 0x7fffu + ((u >> 16) & 1u)) >> 16;  // RNE
  return (short)r;
}
__device__ __forceinline__ float bf2f(short s) {
  unsigned u = ((unsigned)(unsigned short)s) << 16;
  return __builtin_bit_cast(float, u);
}
__device__ __forceinline__ float sigm_f(float x) {
  return __builtin_amdgcn_rcpf(1.0f + __expf(-x));
}
__device__ __forceinline__ float tanh_f(float x) {
  return 1.0f - 2.0f * __builtin_amdgcn_rcpf(1.0f + __expf(2.0f * x));
}
// neighbor value across lane bit0 (parity pair): quad_perm [1,0,3,2]
__device__ __forceinline__ float dpp_xor1(float v) {
  int o = __builtin_amdgcn_mov_dpp(__builtin_bit_cast(int, v), 0xB1, 0xF, 0xF, true);
  return __builtin_bit_cast(float, o);
}

// ---- pre-pass: pack x into B-fragment packets, col parity = hi/lo part ----
__global__ __launch_bounds__(256, 4) void xconv(const float* __restrict__ x,
                                                short* __restrict__ xf) {
  const int gid = blockIdx.x * 256 + threadIdx.x;
  const int l   = gid & 63;
  const int t   = (gid >> 6) & (T_LEN - 1);
  const int blk = gid >> 16;
  const int part = l & 1, ch = (l >> 1) & 7, f0 = (l >> 4) * 8;
  const float* src = x + ((size_t)(blk * NCH + ch) * T_LEN + t) * H + f0;
  float4 v0 = *reinterpret_cast<const float4*>(src);
  float4 v1 = *reinterpret_cast<const float4*>(src + 4);
  float4 v2 = *reinterpret_cast<const float4*>(src + 32);
  float4 v3 = *reinterpret_cast<const float4*>(src + 36);
  float a[8]  = {v0.x, v0.y, v0.z, v0.w, v1.x, v1.y, v1.z, v1.w};
  float c8[8] = {v2.x, v2.y, v2.z, v2.w, v3.x, v3.y, v3.z, v3.w};
  bf16x8 p0, p1;
#pragma unroll
  for (int e = 0; e < 8; ++e) {
    short h0 = f2bf(a[e]);
    short h1 = f2bf(c8[e]);
    if (part == 0) { p0[e] = h0; p1[e] = h1; }
    else { p0[e] = f2bf(a[e] - bf2f(h0)); p1[e] = f2bf(c8[e] - bf2f(h1)); }
  }
  short* dst = xf + (size_t)blk * XBLK_SHORTS + (size_t)t * XT_SHORTS + l * 8;
  *reinterpret_cast<bf16x8*>(dst)       = p0;  // kt0 (feats 0-31)
  *reinterpret_cast<bf16x8*>(dst + 512) = p1;  // kt1 (feats 32-63)
}

__global__ __launch_bounds__(NTHR) void lstm_fused(
    const short* __restrict__ xf,
    const float* __restrict__ w_ih0, const float* __restrict__ w_hh0,
    const float* __restrict__ b_ih0, const float* __restrict__ b_hh0,
    const float* __restrict__ w_ih1, const float* __restrict__ w_hh1,
    const float* __restrict__ b_ih1, const float* __restrict__ b_hh1,
    const float* __restrict__ fc_w, const float* __restrict__ fc_b,
    float* __restrict__ out) {
  const int tid = threadIdx.x;
  const int wv  = tid >> 6;
  const int L   = wv >> 3;   // 0: layer0 waves, 1: layer1 waves
  const int w8  = wv & 7;    // row-block: rows [32*w8, 32*w8+32)
  const int l   = tid & 63;
  const int col = l & 15;    // MFMA column = 2*chain + parity
  const int lq  = l >> 4;
  const int blk = blockIdx.x;

  // h buffers, fragment-linear + XOR swizzle (verified r9/r10)
  __shared__ __align__(16) short hb[2][2][2][520];   // 8320 B
  __shared__ __align__(16) float zp[2][8][260];      // [L][chain][row(+pad)]
  __shared__ float bias_s[2][256];
  __shared__ float fcw_s[H];
  __shared__ float hfin[NCH][H];

  for (int i = tid; i < 2 * 2 * 2 * 520; i += NTHR) ((short*)hb)[i] = 0;
  if (tid < 256)       bias_s[0][tid] = b_ih0[tid] + b_hh0[tid];
  else if (tid < 512)  bias_s[1][tid - 256] = b_ih1[tid - 256] + b_hh1[tid - 256];
  if (tid < H) fcw_s[tid] = fc_w[tid];

  // ---- weights: wave covers rows 32*w8 + 16*rt + col, kt: k0 = 32kt+8lq ----
  const float* wih = L ? w_ih1 : w_ih0;
  const float* whh = L ? w_hh1 : w_hh0;
  bf16x8 whi[2][4], wlo[2][4];  // 64 VGPR
#pragma unroll
  for (int rt = 0; rt < 2; ++rt) {
#pragma unroll
    for (int kt = 0; kt < 4; ++kt) {
      const int row = 32 * w8 + 16 * rt + col;
      const int k0  = 32 * kt + 8 * lq;
      const float* src = (k0 < 64) ? &wih[row * 64 + k0] : &whh[row * 64 + (k0 - 64)];
      float4 v0 = *reinterpret_cast<const float4*>(src);
      float4 v1 = *reinterpret_cast<const float4*>(src + 4);
      float vv[8] = {v0.x, v0.y, v0.z, v0.w, v1.x, v1.y, v1.z, v1.w};
      bf16x8 hi8, lo8;
#pragma unroll
      for (int e = 0; e < 8; ++e) {
        short hh = f2bf(vv[e]);
        hi8[e] = hh;
        lo8[e] = f2bf(vv[e] - bf2f(hh));
      }
      whi[rt][kt] = hi8;
      wlo[rt][kt] = lo8;
    }
  }

  // x-side macro (k-tiles 0,1) into ax; recurrent (k-tiles 2,3) into a.
#define KTX(B0_, B1_)                                               \
  ax0 = MFMA16(whi[0][0], B0_, ax0); ax1 = MFMA16(whi[1][0], B0_, ax1); \
  ax0 = MFMA16(wlo[0][0], B0_, ax0); ax1 = MFMA16(wlo[1][0], B0_, ax1); \
  ax0 = MFMA16(whi[0][1], B1_, ax0); ax1 = MFMA16(whi[1][1], B1_, ax1); \
  ax0 = MFMA16(wlo[0][1], B1_, ax0); ax1 = MFMA16(wlo[1][1], B1_, ax1);
#define KT2(B2_, B3_)                                               \
  a0 = MFMA16(whi[0][2], B2_, a0); a1 = MFMA16(whi[1][2], B2_, a1); \
  a0 = MFMA16(wlo[0][2], B2_, a0); a1 = MFMA16(wlo[1][2], B2_, a1); \
  a0 = MFMA16(whi[0][3], B3_, a0); a1 = MFMA16(whi[1][3], B3_, a1); \
  a0 = MFMA16(wlo[0][3], B3_, a0); a1 = MFMA16(wlo[1][3], B3_, a1);
#define KT4(B0_, B1_, B2_, B3_)                                     \
  a0 = MFMA16(whi[0][0], B0_, a0); a1 = MFMA16(whi[1][0], B0_, a1); \
  a0 = MFMA16(wlo[0][0], B0_, a0); a1 = MFMA16(wlo[1][0], B0_, a1); \
  a0 = MFMA16(whi[0][1], B1_, a0); a1 = MFMA16(whi[1][1], B1_, a1); \
  a0 = MFMA16(wlo[0][1], B1_, a0); a1 = MFMA16(wlo[1][1], B1_, a1); \
  a0 = MFMA16(whi[0][2], B2_, a0); a1 = MFMA16(whi[1][2], B2_, a1); \
  a0 = MFMA16(wlo[0][2], B2_, a0); a1 = MFMA16(wlo[1][2], B2_, a1); \
  a0 = MFMA16(whi[0][3], B3_, a0); a1 = MFMA16(whi[1][3], B3_, a1); \
  a0 = MFMA16(wlo[0][3], B3_, a0); a1 = MFMA16(wlo[1][3], B3_, a1);

  // DPP parity presum + even-lane z write (order (ze+zo) preserved)
#define ZSTORE(Lidx)                                                \
  {                                                                 \
    f32x4 s0, s1;                                                   \
    _Pragma("unroll")                                               \
    for (int r = 0; r < 4; ++r) {                                   \
      s0[r] = a0[r] + dpp_xor1(a0[r]);                              \
      s1[r] = a1[r] + dpp_xor1(a1[r]);                              \
    }                                                               \
    if ((l & 1) == 0) {                                             \
      *reinterpret_cast<f32x4*>(&zp[Lidx][col >> 1][32 * w8 + 4 * lq])      = s0; \
      *reinterpret_cast<f32x4*>(&zp[Lidx][col >> 1][32 * w8 + 16 + 4 * lq]) = s1; \
    }                                                               \
  }

  const f32x4 zf4 = {0.f, 0.f, 0.f, 0.f};

  // ---- L0 prologue: ax = x-side z for step 0 (regs only, pre-barrier) ----
  const short* xfl = xf + (size_t)blk * XBLK_SHORTS + l * 8;
  f32x4 ax0 = zf4, ax1 = zf4;
  bf16x8 xbn0, xbn1;
  if (L == 0) {
    bf16x8 x0 = *reinterpret_cast<const bf16x8*>(xfl);
    bf16x8 x1 = *reinterpret_cast<const bf16x8*>(xfl + 512);
    KTX(x0, x1)
  }

  __syncthreads();  // bias_s / h-buf zeros visible

  // reader LDS offset (shorts): swizzled slot * 8
  const int rdoff = ((l & 48) | ((l & 15) ^ ((l >> 4) << 1))) * 8;
  // gate task: (L, ch, h) = (wave layer, wave&7, lane)
  const int gch = wv & 7, gh = l;
  const int ghalf = gh >> 5, glq = (gh >> 3) & 3, ge = gh & 7;
  const int slot0 = (glq << 4) | (((gch << 1) | 0) ^ (glq << 1));
  const int gw0 = ghalf * 520 + slot0 * 8 + ge;        // hi (p=0)
  const int gw1 = ghalf * 520 + (slot0 | 1) * 8 + ge;  // lo (p=1)
  float cst = 0.0f;

  for (int t = 0; t <= T_LEN; ++t) {
    const int cur = t & 1, nxt = cur ^ 1;

    if (L == 0) {
      if (t + 1 < T_LEN) {  // prefetch x[t+1] packets (consumed in phase 2)
        const short* p = xfl + (size_t)(t + 1) * XT_SHORTS;
        xbn0 = *reinterpret_cast<const bf16x8*>(p);
        xbn1 = *reinterpret_cast<const bf16x8*>(p + 512);
      }
      if (t < T_LEN) {
        const short* h0c = &hb[0][cur][0][0];
        bf16x8 B2 = *reinterpret_cast<const bf16x8*>(h0c + rdoff);
        bf16x8 B3 = *reinterpret_cast<const bf16x8*>(h0c + 520 + rdoff);
        f32x4 a0 = ax0, a1 = ax1;  // x-side precomputed (acc order == r10)
        KT2(B2, B3)
        ZSTORE(0)
      }
    } else {
      if (t >= 1) {
        const short* h0c = &hb[0][cur][0][0];
        const short* h1c = &hb[1][cur][0][0];
        bf16x8 B0 = *reinterpret_cast<const bf16x8*>(h0c + rdoff);
        bf16x8 B1 = *reinterpret_cast<const bf16x8*>(h0c + 520 + rdoff);
        bf16x8 B2 = *reinterpret_cast<const bf16x8*>(h1c + rdoff);
        bf16x8 B3 = *reinterpret_cast<const bf16x8*>(h1c + 520 + rdoff);
        f32x4 a0 = zf4, a1 = zf4;
        KT4(B0, B1, B2, B3)
        ZSTORE(1)
      }
    }

    __syncthreads();  // z ready

    // phase 2: L0 waves interleave next-step x-side MFMA with gate VALU
    if (L == 0 && t + 1 < T_LEN) {
      ax0 = zf4; ax1 = zf4;
      KTX(xbn0, xbn1)
    }

    const bool act = (L == 0) ? (t < T_LEN) : (t >= 1);
    if (act) {
      const float* zrow = &zp[L][gch][0];  // parity already summed
      float z0 = zrow[gh]       + bias_s[L][gh];
      float z1 = zrow[64 + gh]  + bias_s[L][64 + gh];
      float z2 = zrow[128 + gh] + bias_s[L][128 + gh];
      float z3 = zrow[192 + gh] + bias_s[L][192 + gh];
      float ig = sigm_f(z0), fg = sigm_f(z1);
      float gg = tanh_f(z2), og = sigm_f(z3);
      cst = fg * cst + ig * gg;
      float hv = og * tanh_f(cst);
      if (L == 1 && t == T_LEN) {
        hfin[gch][gh] = hv;
      } else {
        short hi = f2bf(hv);
        short lo = f2bf(hv - bf2f(hi));
        short* base = &hb[L][nxt][0][0];
        base[gw0] = hi;
        base[gw1] = lo;
      }
    }

    __syncthreads();  // h[nxt] ready
  }
#undef KT4
#undef KT2
#undef KTX
#undef ZSTORE

  // ---- FC epilogue ----
  if (tid < NCH) {
    float acc = fc_b[0];
#pragma unroll
    for (int h = 0; h < H; ++h) acc += fcw_s[h] * hfin[tid][h];
    out[blk * NCH + tid] = acc;
  }
}

extern "C" void kernel_launch(void* const* d_in, const int* in_sizes, int n_in,
                              void* d_out, int out_size, void* d_ws, size_t ws_size,
                              hipStream_t stream) {
  const float* x     = (const float*)d_in[0];
  const float* w_ih0 = (const float*)d_in[1];
  const float* w_hh0 = (const float*)d_in[2];
  const float* b_ih0 = (const float*)d_in[3];
  const float* b_hh0 = (const float*)d_in[4];
  const float* w_ih1 = (const float*)d_in[5];
  const float* w_hh1 = (const float*)d_in[6];
  const float* b_ih1 = (const float*)d_in[7];
  const float* b_hh1 = (const float*)d_in[8];
  const float* fc_w  = (const float*)d_in[9];
  const float* fc_b  = (const float*)d_in[10];
  float* out = (float*)d_out;

  short* xfrag = (short*)d_ws;  // 128 MiB exactly

  xconv<<<dim3(16384), dim3(256), 0, stream>>>(x, xfrag);
  lstm_fused<<<dim3(NBLK), dim3(NTHR), 0, stream>>>(
      xfrag, w_ih0, w_hh0, b_ih0, b_hh0, w_ih1, w_hh1, b_ih1, b_hh1,
      fc_w, fc_b, out);
}

// Round 14
// 1074.896 us; speedup vs baseline: 1.2706x; 1.0179x over previous
//
#include <hip/hip_runtime.h>
#include <hip/hip_bf16.h>

// LSTMReg on MI355X — round 14: LAYER-STAGGERED PHASES on the r13 skeleton.
// r13 audit: MFMA (1242 cyc/SIMD-iter) and gate VALU (~700) run in SERIAL
// phases -> iter 2400. Stagger the layers so every phase has both: 16 waves,
// wv0-7 = L0, wv8-15 = L1 (2+2 per SIMD).
//   Phase A: L0 MFMA(t)      || L1 gates(t-2)  [z from zp[1], h1[t-2] out]
//   Phase B: L0 gates(t)     || L1 MFMA(t-1)   [z to zp[1]]
// Unlike r12 (which failed): gates are zp-deduplicated (1 task/thread, not
// 8x parity-redundant) and 4 waves/SIMD. All verified maps kept; L0 uses
// r9's KT4 order -> bit-exact (absmax 0.0 expected).

typedef short bf16x8 __attribute__((ext_vector_type(8)));
typedef float f32x4  __attribute__((ext_vector_type(4)));

#define MFMA16(A, B, C) __builtin_amdgcn_mfma_f32_16x16x32_bf16(A, B, C, 0, 0, 0)

constexpr int T_LEN = 1024;
constexpr int H     = 64;
constexpr int NCH   = 8;     // chains per block
constexpr int NTHR  = 1024;  // 16 waves
constexpr int NBLK  = 64;    // 512 chains / 8

// x fragment buffer: [blk][t][kt(2)][lane(64)][8 shorts]
constexpr int    XT_SHORTS   = 2 * 64 * 8;                 // 1024 shorts per t
constexpr size_t XBLK_SHORTS = (size_t)T_LEN * XT_SHORTS;  // 2 MiB per block

__device__ __forceinline__ short f2bf(float f) {
  unsigned u = __builtin_bit_cast(unsigned, f);
  unsigned r = (u + 0x7fffu + ((u >> 16) & 1u)) >> 16;  // RNE
  return (short)r;
}
__device__ __forceinline__ float bf2f(short s) {
  unsigned u = ((unsigned)(unsigned short)s) << 16;
  return __builtin_bit_cast(float, u);
}
__device__ __forceinline__ float sigm_f(float x) {
  return __builtin_amdgcn_rcpf(1.0f + __expf(-x));
}
__device__ __forceinline__ float tanh_f(float x) {
  return 1.0f - 2.0f * __builtin_amdgcn_rcpf(1.0f + __expf(2.0f * x));
}
// neighbor value across lane bit0 (parity pair): quad_perm [1,0,3,2]
__device__ __forceinline__ float dpp_xor1(float v) {
  int o = __builtin_amdgcn_mov_dpp(__builtin_bit_cast(int, v), 0xB1, 0xF, 0xF, true);
  return __builtin_bit_cast(float, o);
}

// ---- pre-pass: pack x into B-fragment packets, col parity = hi/lo part ----
__global__ __launch_bounds__(256, 4) void xconv(const float* __restrict__ x,
                                                short* __restrict__ xf) {
  const int gid = blockIdx.x * 256 + threadIdx.x;
  const int l   = gid & 63;
  const int t   = (gid >> 6) & (T_LEN - 1);
  const int blk = gid >> 16;
  const int part = l & 1, ch = (l >> 1) & 7, f0 = (l >> 4) * 8;
  const float* src = x + ((size_t)(blk * NCH + ch) * T_LEN + t) * H + f0;
  float4 v0 = *reinterpret_cast<const float4*>(src);
  float4 v1 = *reinterpret_cast<const float4*>(src + 4);
  float4 v2 = *reinterpret_cast<const float4*>(src + 32);
  float4 v3 = *reinterpret_cast<const float4*>(src + 36);
  float a[8]  = {v0.x, v0.y, v0.z, v0.w, v1.x, v1.y, v1.z, v1.w};
  float c8[8] = {v2.x, v2.y, v2.z, v2.w, v3.x, v3.y, v3.z, v3.w};
  bf16x8 p0, p1;
#pragma unroll
  for (int e = 0; e < 8; ++e) {
    short h0 = f2bf(a[e]);
    short h1 = f2bf(c8[e]);
    if (part == 0) { p0[e] = h0; p1[e] = h1; }
    else { p0[e] = f2bf(a[e] - bf2f(h0)); p1[e] = f2bf(c8[e] - bf2f(h1)); }
  }
  short* dst = xf + (size_t)blk * XBLK_SHORTS + (size_t)t * XT_SHORTS + l * 8;
  *reinterpret_cast<bf16x8*>(dst)       = p0;  // kt0 (feats 0-31)
  *reinterpret_cast<bf16x8*>(dst + 512) = p1;  // kt1 (feats 32-63)
}

__global__ __launch_bounds__(NTHR) void lstm_fused(
    const short* __restrict__ xf,
    const float* __restrict__ w_ih0, const float* __restrict__ w_hh0,
    const float* __restrict__ b_ih0, const float* __restrict__ b_hh0,
    const float* __restrict__ w_ih1, const float* __restrict__ w_hh1,
    const float* __restrict__ b_ih1, const float* __restrict__ b_hh1,
    const float* __restrict__ fc_w, const float* __restrict__ fc_b,
    float* __restrict__ out) {
  const int tid = threadIdx.x;
  const int wv  = tid >> 6;
  const int L   = wv >> 3;   // 0: layer0 waves (wv0-7), 1: layer1 (wv8-15)
  const int w8  = wv & 7;    // row-block: rows [32*w8, 32*w8+32)
  const int l   = tid & 63;
  const int col = l & 15;    // MFMA column = 2*chain + parity
  const int lq  = l >> 4;
  const int blk = blockIdx.x;

  // h buffers, fragment-linear + XOR swizzle (verified r9-r13)
  __shared__ __align__(16) short hb[2][2][2][520];   // [layer][buf][half][520]
  __shared__ __align__(16) float zp[2][8][260];      // [L][chain][row(+pad)]
  __shared__ float bias_s[2][256];
  __shared__ float fcw_s[H];
  __shared__ float hfin[NCH][H];

  for (int i = tid; i < 2 * 2 * 2 * 520; i += NTHR) ((short*)hb)[i] = 0;
  if (tid < 256)       bias_s[0][tid] = b_ih0[tid] + b_hh0[tid];
  else if (tid < 512)  bias_s[1][tid - 256] = b_ih1[tid - 256] + b_hh1[tid - 256];
  if (tid < H) fcw_s[tid] = fc_w[tid];

  // ---- weights: wave covers rows 32*w8 + 16*rt + col, kt: k0 = 32kt+8lq ----
  const float* wih = L ? w_ih1 : w_ih0;
  const float* whh = L ? w_hh1 : w_hh0;
  bf16x8 whi[2][4], wlo[2][4];  // 64 VGPR
#pragma unroll
  for (int rt = 0; rt < 2; ++rt) {
#pragma unroll
    for (int kt = 0; kt < 4; ++kt) {
      const int row = 32 * w8 + 16 * rt + col;
      const int k0  = 32 * kt + 8 * lq;
      const float* src = (k0 < 64) ? &wih[row * 64 + k0] : &whh[row * 64 + (k0 - 64)];
      float4 v0 = *reinterpret_cast<const float4*>(src);
      float4 v1 = *reinterpret_cast<const float4*>(src + 4);
      float vv[8] = {v0.x, v0.y, v0.z, v0.w, v1.x, v1.y, v1.z, v1.w};
      bf16x8 hi8, lo8;
#pragma unroll
      for (int e = 0; e < 8; ++e) {
        short hh = f2bf(vv[e]);
        hi8[e] = hh;
        lo8[e] = f2bf(vv[e] - bf2f(hh));
      }
      whi[rt][kt] = hi8;
      wlo[rt][kt] = lo8;
    }
  }

#define KT4(B0_, B1_, B2_, B3_)                                     \
  a0 = MFMA16(whi[0][0], B0_, a0); a1 = MFMA16(whi[1][0], B0_, a1); \
  a0 = MFMA16(wlo[0][0], B0_, a0); a1 = MFMA16(wlo[1][0], B0_, a1); \
  a0 = MFMA16(whi[0][1], B1_, a0); a1 = MFMA16(whi[1][1], B1_, a1); \
  a0 = MFMA16(wlo[0][1], B1_, a0); a1 = MFMA16(wlo[1][1], B1_, a1); \
  a0 = MFMA16(whi[0][2], B2_, a0); a1 = MFMA16(whi[1][2], B2_, a1); \
  a0 = MFMA16(wlo[0][2], B2_, a0); a1 = MFMA16(wlo[1][2], B2_, a1); \
  a0 = MFMA16(whi[0][3], B3_, a0); a1 = MFMA16(whi[1][3], B3_, a1); \
  a0 = MFMA16(wlo[0][3], B3_, a0); a1 = MFMA16(wlo[1][3], B3_, a1);

  // DPP parity presum + even-lane z write (order (ze+zo) preserved)
#define ZSTORE(Lidx)                                                \
  {                                                                 \
    f32x4 s0, s1;                                                   \
    _Pragma("unroll")                                               \
    for (int r = 0; r < 4; ++r) {                                   \
      s0[r] = a0[r] + dpp_xor1(a0[r]);                              \
      s1[r] = a1[r] + dpp_xor1(a1[r]);                              \
    }                                                               \
    if ((l & 1) == 0) {                                             \
      *reinterpret_cast<f32x4*>(&zp[Lidx][col >> 1][32 * w8 + 4 * lq])      = s0; \
      *reinterpret_cast<f32x4*>(&zp[Lidx][col >> 1][32 * w8 + 16 + 4 * lq]) = s1; \
    }                                                               \
  }

  // gates: one (ch,h) task per thread from zp[Lidx] (parity pre-summed)
#define GATES(Lidx, hv_)                                            \
  {                                                                 \
    const float* zrow = &zp[Lidx][gch][0];                          \
    float z0 = zrow[gh]       + bias_s[Lidx][gh];                   \
    float z1 = zrow[64 + gh]  + bias_s[Lidx][64 + gh];              \
    float z2 = zrow[128 + gh] + bias_s[Lidx][128 + gh];             \
    float z3 = zrow[192 + gh] + bias_s[Lidx][192 + gh];             \
    float ig = sigm_f(z0), fg = sigm_f(z1);                         \
    float gg = tanh_f(z2), og = sigm_f(z3);                         \
    cst = fg * cst + ig * gg;                                       \
    hv_ = og * tanh_f(cst);                                         \
  }

  const f32x4 zf4 = {0.f, 0.f, 0.f, 0.f};

  __syncthreads();  // bias_s / h-buf zeros visible

  // reader LDS offset (shorts): swizzled slot * 8
  const int rdoff = ((l & 48) | ((l & 15) ^ ((l >> 4) << 1))) * 8;
  // gate task: (ch, h) = (wave&7, lane); layer = wave group L
  const int gch = wv & 7, gh = l;
  const int ghalf = gh >> 5, glq = (gh >> 3) & 3, ge = gh & 7;
  const int slot0 = (glq << 4) | (((gch << 1) | 0) ^ (glq << 1));
  const int gw0 = ghalf * 520 + slot0 * 8 + ge;        // hi (p=0)
  const int gw1 = ghalf * 520 + (slot0 | 1) * 8 + ge;  // lo (p=1)
  float cst = 0.0f;

  // x prefetch (L0 waves): xb = x[0]
  const short* xfl = xf + (size_t)blk * XBLK_SHORTS + l * 8;
  bf16x8 xb0, xb1, xbn0, xbn1;
  if (L == 0) {
    xb0 = *reinterpret_cast<const bf16x8*>(xfl);
    xb1 = *reinterpret_cast<const bf16x8*>(xfl + 512);
  }

  for (int t = 0; t <= T_LEN + 1; ++t) {
    // ========== Phase A: L0 MFMA(t) || L1 gates(t-2) ==========
    if (L == 0) {
      if (t + 1 < T_LEN) {  // issue x[t+1] loads early
        const short* p = xfl + (size_t)(t + 1) * XT_SHORTS;
        xbn0 = *reinterpret_cast<const bf16x8*>(p);
        xbn1 = *reinterpret_cast<const bf16x8*>(p + 512);
      }
      if (t < T_LEN) {
        const short* h0c = &hb[0][(t + 1) & 1][0][0];  // h0[t-1]
        bf16x8 B2 = *reinterpret_cast<const bf16x8*>(h0c + rdoff);
        bf16x8 B3 = *reinterpret_cast<const bf16x8*>(h0c + 520 + rdoff);
        f32x4 a0 = zf4, a1 = zf4;
        KT4(xb0, xb1, B2, B3)
        ZSTORE(0)
      }
    } else {
      if (t >= 2) {  // gates for L1 step t-2 (z written last Phase B)
        float hv;
        GATES(1, hv)
        if (t == T_LEN + 1) {
          hfin[gch][gh] = hv;
        } else {
          short hi = f2bf(hv);
          short lo = f2bf(hv - bf2f(hi));
          short* base = &hb[1][t & 1][0][0];  // h1[t-2], buf (t-2)&1 == t&1
          base[gw0] = hi;
          base[gw1] = lo;
        }
      }
    }

    __syncthreads();

    // ========== Phase B: L0 gates(t) || L1 MFMA(t-1) ==========
    if (L == 0) {
      if (t < T_LEN) {
        float hv;
        GATES(0, hv)
        short hi = f2bf(hv);
        short lo = f2bf(hv - bf2f(hi));
        short* base = &hb[0][t & 1][0][0];    // h0[t]
        base[gw0] = hi;
        base[gw1] = lo;
      }
    } else {
      if (t >= 1 && t <= T_LEN) {
        const short* h0c = &hb[0][(t + 1) & 1][0][0];  // h0[t-1]
        const short* h1c = &hb[1][t & 1][0][0];        // h1[t-2]
        bf16x8 B0 = *reinterpret_cast<const bf16x8*>(h0c + rdoff);
        bf16x8 B1 = *reinterpret_cast<const bf16x8*>(h0c + 520 + rdoff);
        bf16x8 B2 = *reinterpret_cast<const bf16x8*>(h1c + rdoff);
        bf16x8 B3 = *reinterpret_cast<const bf16x8*>(h1c + 520 + rdoff);
        f32x4 a0 = zf4, a1 = zf4;
        KT4(B0, B1, B2, B3)
        ZSTORE(1)
      }
    }

    __syncthreads();
    if (L == 0) { xb0 = xbn0; xb1 = xbn1; }
  }
#undef KT4
#undef ZSTORE
#undef GATES

  // ---- FC epilogue ----
  if (tid < NCH) {
    float acc = fc_b[0];
#pragma unroll
    for (int h = 0; h < H; ++h) acc += fcw_s[h] * hfin[tid][h];
    out[blk * NCH + tid] = acc;
  }
}

extern "C" void kernel_launch(void* const* d_in, const int* in_sizes, int n_in,
                              void* d_out, int out_size, void* d_ws, size_t ws_size,
                              hipStream_t stream) {
  const float* x     = (const float*)d_in[0];
  const float* w_ih0 = (const float*)d_in[1];
  const float* w_hh0 = (const float*)d_in[2];
  const float* b_ih0 = (const float*)d_in[3];
  const float* b_hh0 = (const float*)d_in[4];
  const float* w_ih1 = (const float*)d_in[5];
  const float* w_hh1 = (const float*)d_in[6];
  const float* b_ih1 = (const float*)d_in[7];
  const float* b_hh1 = (const float*)d_in[8];
  const float* fc_w  = (const float*)d_in[9];
  const float* fc_b  = (const float*)d_in[10];
  float* out = (float*)d_out;

  short* xfrag = (short*)d_ws;  // 128 MiB exactly

  xconv<<<dim3(16384), dim3(256), 0, stream>>>(x, xfrag);
  lstm_fused<<<dim3(NBLK), dim3(NTHR), 0, stream>>>(
      xfrag, w_ih0, w_hh0, b_ih0, b_hh0, w_ih1, w_hh1, b_ih1, b_hh1,
      fc_w, fc_b, out);
}

// Round 15
// 824.876 us; speedup vs baseline: 1.6557x; 1.3031x over previous
//
#include <hip/hip_runtime.h>
#include <hip/hip_bf16.h>

// LSTMReg on MI355X — round 15: SINGLE-PASS FP16 (halve the MFMA count).
// r10/r13/r14 all pinned at ~2300 cyc/iter: MFMA issue 1242 (2-pass bf16
// hi/lo) + ~1000 latency/gates. fp16 has 11 mantissa bits -> single-pass
// product rel-err ~2^-11; scaling r2's measured 2.4e-7 (eff 2^-17) by 2^6
// predicts absmax ~1.5e-5 << 1.5e-3 threshold. MFMA/SIMD-iter: 1242 -> 622.
// Columns = chains (8 used, 8 idle); no parity machinery; h stored as
// single fp16 (lane-linear packed b32 writes via DPP pair-pack). r14's
// staggered phase skeleton kept: A = L0 MFMA(t) || L1 gates(t-2);
// B = L0 gates(t) || L1 MFMA(t-1). 64 blocks x 16 waves.

typedef _Float16 f16x8 __attribute__((ext_vector_type(8)));
typedef float f32x4  __attribute__((ext_vector_type(4)));

#define MFMAH(A, B, C) __builtin_amdgcn_mfma_f32_16x16x32_f16(A, B, C, 0, 0, 0)

constexpr int T_LEN = 1024;
constexpr int H     = 64;
constexpr int NCH   = 8;     // chains per block
constexpr int NTHR  = 1024;  // 16 waves
constexpr int NBLK  = 64;    // 512 chains / 8

// x fragment buffer: [blk][t][kt(2)][lq(4)][ch(8)][8 halfs]
constexpr int    XT_HALFS   = 2 * 4 * 8 * 8;                // 512 halfs per t
constexpr size_t XBLK_HALFS = (size_t)T_LEN * XT_HALFS;     // 1 MiB per block

__device__ __forceinline__ float sigm_f(float x) {
  return __builtin_amdgcn_rcpf(1.0f + __expf(-x));
}
__device__ __forceinline__ float tanh_f(float x) {
  return 1.0f - 2.0f * __builtin_amdgcn_rcpf(1.0f + __expf(2.0f * x));
}
// neighbor value across lane bit0: quad_perm [1,0,3,2]
__device__ __forceinline__ unsigned dpp_xor1_u32(unsigned v) {
  return (unsigned)__builtin_amdgcn_mov_dpp((int)v, 0xB1, 0xF, 0xF, true);
}

// ---- pre-pass: x [512][1024][64] fp32 -> fp16 fragment packets ----
__global__ __launch_bounds__(256, 4) void xconv(const float* __restrict__ x,
                                                _Float16* __restrict__ xf) {
  const int gid = blockIdx.x * 256 + threadIdx.x;  // (chain, t, lq)
  const int lq    = gid & 3;
  const int t     = (gid >> 2) & (T_LEN - 1);
  const int chain = gid >> 12;                     // 0..511
  const int ch  = chain & 7;
  const int blk = chain >> 3;
  const float* src = x + ((size_t)chain * T_LEN + t) * H + 8 * lq;
  float4 v0 = *reinterpret_cast<const float4*>(src);
  float4 v1 = *reinterpret_cast<const float4*>(src + 4);
  float4 v2 = *reinterpret_cast<const float4*>(src + 32);
  float4 v3 = *reinterpret_cast<const float4*>(src + 36);
  float a[8]  = {v0.x, v0.y, v0.z, v0.w, v1.x, v1.y, v1.z, v1.w};
  float c8[8] = {v2.x, v2.y, v2.z, v2.w, v3.x, v3.y, v3.z, v3.w};
  f16x8 p0, p1;
#pragma unroll
  for (int e = 0; e < 8; ++e) {
    p0[e] = (_Float16)a[e];   // RNE v_cvt_f16_f32
    p1[e] = (_Float16)c8[e];
  }
  _Float16* dst = xf + (size_t)blk * XBLK_HALFS + (size_t)t * XT_HALFS +
                  lq * 64 + ch * 8;
  *reinterpret_cast<f16x8*>(dst)       = p0;  // kt0 (feats 0-31)
  *reinterpret_cast<f16x8*>(dst + 256) = p1;  // kt1 (feats 32-63)
}

__global__ __launch_bounds__(NTHR) void lstm_fused(
    const _Float16* __restrict__ xf,
    const float* __restrict__ w_ih0, const float* __restrict__ w_hh0,
    const float* __restrict__ b_ih0, const float* __restrict__ b_hh0,
    const float* __restrict__ w_ih1, const float* __restrict__ w_hh1,
    const float* __restrict__ b_ih1, const float* __restrict__ b_hh1,
    const float* __restrict__ fc_w, const float* __restrict__ fc_b,
    float* __restrict__ out) {
  const int tid = threadIdx.x;
  const int wv  = tid >> 6;
  const int L   = wv >> 3;   // 0: layer0 waves (wv0-7), 1: layer1 (wv8-15)
  const int w8  = wv & 7;    // row-block: rows [32*w8, 32*w8+32)
  const int l   = tid & 63;
  const int col = l & 15;    // MFMA column; chains are cols 0-7 (8-15 idle)
  const int lq  = l >> 4;
  const int blk = blockIdx.x;

  // h buffers: [layer][buf][kt(2)][lq(4)][ch(8)][e(8)] halfs = 1 KiB each
  __shared__ __align__(16) _Float16 hb[2][2][512];
  __shared__ __align__(16) float zp[2][8][260];   // [L][chain][row(+pad)]
  __shared__ float bias_s[2][256];
  __shared__ float fcw_s[H];
  __shared__ float hfin[NCH][H];

  for (int i = tid; i < 2 * 2 * 512; i += NTHR) ((_Float16*)hb)[i] = (_Float16)0.f;
  if (tid < 256)       bias_s[0][tid] = b_ih0[tid] + b_hh0[tid];
  else if (tid < 512)  bias_s[1][tid - 256] = b_ih1[tid - 256] + b_hh1[tid - 256];
  if (tid < H) fcw_s[tid] = fc_w[tid];

  // ---- weights (single fp16): rows 32*w8 + 16*rt + (l&15); k0 = 32kt+8lq ----
  const float* wih = L ? w_ih1 : w_ih0;
  const float* whh = L ? w_hh1 : w_hh0;
  f16x8 w16[2][4];  // [rt][kt] = 32 VGPR
#pragma unroll
  for (int rt = 0; rt < 2; ++rt) {
#pragma unroll
    for (int kt = 0; kt < 4; ++kt) {
      const int row = 32 * w8 + 16 * rt + col;
      const int k0  = 32 * kt + 8 * lq;
      const float* src = (k0 < 64) ? &wih[row * 64 + k0] : &whh[row * 64 + (k0 - 64)];
      float4 v0 = *reinterpret_cast<const float4*>(src);
      float4 v1 = *reinterpret_cast<const float4*>(src + 4);
      float vv[8] = {v0.x, v0.y, v0.z, v0.w, v1.x, v1.y, v1.z, v1.w};
      f16x8 h8;
#pragma unroll
      for (int e = 0; e < 8; ++e) h8[e] = (_Float16)vv[e];
      w16[rt][kt] = h8;
    }
  }

  __syncthreads();  // hb zeros / bias visible

  // B-frag LDS offset (halfs): kt*256 + lq*64 + (col&7)*8
  const int rdoff = lq * 64 + (col & 7) * 8;
  // gate task: (ch, f) = (l>>3, w8*8 + (l&7)); h-write is lane-linear at
  // w8*64 + l (halfs) in the [kt][lq][ch][e] layout.
  const int gch = l >> 3;
  const int gf  = w8 * 8 + (l & 7);
  const int hword = w8 * 32 + (l >> 1);  // packed-b32 word index
  float cst = 0.0f;

  // x prefetch (L0 waves)
  const _Float16* xfl = xf + (size_t)blk * XBLK_HALFS + rdoff;
  f16x8 xb0, xb1, xbn0, xbn1;
  if (L == 0) {
    xb0 = *reinterpret_cast<const f16x8*>(xfl);
    xb1 = *reinterpret_cast<const f16x8*>(xfl + 256);
  }

  const f32x4 zf4 = {0.f, 0.f, 0.f, 0.f};

#define ZSTORE(Lidx)                                                       \
  if (col < 8) {                                                           \
    *reinterpret_cast<f32x4*>(&zp[Lidx][col][32 * w8 + 4 * lq])      = a0; \
    *reinterpret_cast<f32x4*>(&zp[Lidx][col][32 * w8 + 16 + 4 * lq]) = a1; \
  }

#define GATES(Lidx, hv_)                                            \
  {                                                                 \
    const float* zrow = &zp[Lidx][gch][0];                          \
    float z0 = zrow[gf]       + bias_s[Lidx][gf];                   \
    float z1 = zrow[64 + gf]  + bias_s[Lidx][64 + gf];              \
    float z2 = zrow[128 + gf] + bias_s[Lidx][128 + gf];             \
    float z3 = zrow[192 + gf] + bias_s[Lidx][192 + gf];             \
    float ig = sigm_f(z0), fg = sigm_f(z1);                         \
    float gg = tanh_f(z2), og = sigm_f(z3);                         \
    cst = fg * cst + ig * gg;                                       \
    hv_ = og * tanh_f(cst);                                         \
  }

  // even lane packs (own, neighbor) halves -> one conflict-free b32 write
#define HSTORE(base_, hv_)                                          \
  {                                                                 \
    _Float16 hf = (_Float16)(hv_);                                  \
    unsigned me = (unsigned)__builtin_bit_cast(unsigned short, hf); \
    unsigned nb = dpp_xor1_u32(me);                                 \
    if ((l & 1) == 0)                                               \
      reinterpret_cast<unsigned*>(base_)[hword] = me | (nb << 16);  \
  }

  for (int t = 0; t <= T_LEN + 1; ++t) {
    // ========== Phase A: L0 MFMA(t) || L1 gates(t-2) ==========
    if (L == 0) {
      if (t + 1 < T_LEN) {
        const _Float16* p = xfl + (size_t)(t + 1) * XT_HALFS;
        xbn0 = *reinterpret_cast<const f16x8*>(p);
        xbn1 = *reinterpret_cast<const f16x8*>(p + 256);
      }
      if (t < T_LEN) {
        const _Float16* h0c = &hb[0][(t + 1) & 1][0];  // h0[t-1]
        f16x8 B2 = *reinterpret_cast<const f16x8*>(h0c + rdoff);
        f16x8 B3 = *reinterpret_cast<const f16x8*>(h0c + 256 + rdoff);
        f32x4 a0 = zf4, a1 = zf4;
        a0 = MFMAH(w16[0][0], xb0, a0); a1 = MFMAH(w16[1][0], xb0, a1);
        a0 = MFMAH(w16[0][1], xb1, a0); a1 = MFMAH(w16[1][1], xb1, a1);
        a0 = MFMAH(w16[0][2], B2,  a0); a1 = MFMAH(w16[1][2], B2,  a1);
        a0 = MFMAH(w16[0][3], B3,  a0); a1 = MFMAH(w16[1][3], B3,  a1);
        ZSTORE(0)
      }
    } else {
      if (t >= 2) {  // gates for L1 step t-2 (z from last Phase B)
        float hv;
        GATES(1, hv)
        if (t == T_LEN + 1) {
          hfin[gch][gf] = hv;
        } else {
          HSTORE(&hb[1][t & 1][0], hv)  // h1[t-2], buf (t-2)&1 == t&1
        }
      }
    }

    __syncthreads();

    // ========== Phase B: L0 gates(t) || L1 MFMA(t-1) ==========
    if (L == 0) {
      if (t < T_LEN) {
        float hv;
        GATES(0, hv)
        HSTORE(&hb[0][t & 1][0], hv)    // h0[t]
      }
    } else {
      if (t >= 1 && t <= T_LEN) {
        const _Float16* h0c = &hb[0][(t + 1) & 1][0];  // h0[t-1]
        const _Float16* h1c = &hb[1][t & 1][0];        // h1[t-2]
        f16x8 B0 = *reinterpret_cast<const f16x8*>(h0c + rdoff);
        f16x8 B1 = *reinterpret_cast<const f16x8*>(h0c + 256 + rdoff);
        f16x8 B2 = *reinterpret_cast<const f16x8*>(h1c + rdoff);
        f16x8 B3 = *reinterpret_cast<const f16x8*>(h1c + 256 + rdoff);
        f32x4 a0 = zf4, a1 = zf4;
        a0 = MFMAH(w16[0][0], B0, a0); a1 = MFMAH(w16[1][0], B0, a1);
        a0 = MFMAH(w16[0][1], B1, a0); a1 = MFMAH(w16[1][1], B1, a1);
        a0 = MFMAH(w16[0][2], B2, a0); a1 = MFMAH(w16[1][2], B2, a1);
        a0 = MFMAH(w16[0][3], B3, a0); a1 = MFMAH(w16[1][3], B3, a1);
        ZSTORE(1)
      }
    }

    __syncthreads();
    if (L == 0) { xb0 = xbn0; xb1 = xbn1; }
  }
#undef ZSTORE
#undef GATES
#undef HSTORE

  // ---- FC epilogue ----
  if (tid < NCH) {
    float acc = fc_b[0];
#pragma unroll
    for (int h = 0; h < H; ++h) acc += fcw_s[h] * hfin[tid][h];
    out[blk * NCH + tid] = acc;
  }
}

extern "C" void kernel_launch(void* const* d_in, const int* in_sizes, int n_in,
                              void* d_out, int out_size, void* d_ws, size_t ws_size,
                              hipStream_t stream) {
  const float* x     = (const float*)d_in[0];
  const float* w_ih0 = (const float*)d_in[1];
  const float* w_hh0 = (const float*)d_in[2];
  const float* b_ih0 = (const float*)d_in[3];
  const float* b_hh0 = (const float*)d_in[4];
  const float* w_ih1 = (const float*)d_in[5];
  const float* w_hh1 = (const float*)d_in[6];
  const float* b_ih1 = (const float*)d_in[7];
  const float* b_hh1 = (const float*)d_in[8];
  const float* fc_w  = (const float*)d_in[9];
  const float* fc_b  = (const float*)d_in[10];
  float* out = (float*)d_out;

  _Float16* xfrag = (_Float16*)d_ws;  // 64 MiB used of workspace

  // 512 chains * 1024 t * 4 lq = 2,097,152 threads / 256 = 8192 blocks
  xconv<<<dim3(8192), dim3(256), 0, stream>>>(x, xfrag);
  lstm_fused<<<dim3(NBLK), dim3(NTHR), 0, stream>>>(
      xfrag, w_ih0, w_hh0, b_ih0, b_hh0, w_ih1, w_hh1, b_ih1, b_hh1,
      fc_w, fc_b, out);
}